// Round 1
// baseline (273.296 us; speedup 1.0000x reference)
//
#include <hip/hip_runtime.h>
#include <hip/hip_bf16.h>

// AttentionBlock: S=4096, D=1024, H=16, hd=64. fp32 in/out, bf16 MFMA internally.
// ws layout (48 MB):
//   [ 0, 8)MB  Xr : RoPE'd input, bf16 [4096][1024]
//   [ 8,16)MB  Wb : Wq|Wk|Wv|Wo bf16, each [1024][1024] (N x K row-major)
//   [16,24)MB  Q  : bf16 [4096][1024] (pre-scaled by 0.125*log2(e))
//   [24,32)MB  K  : bf16 [4096][1024]
//   [32,40)MB  Vt : bf16 [1024][4096]  == V^T  (row = h*64+d, col = seq)
//   [40,48)MB  Ab : attn out bf16 [4096][1024]
// Softmax: fixed-max. p = exp2(S - 16*log2e) with 0.125*log2e folded into Q.
// Round 7: occupancy restructure of attn. 512-thread blocks, 8 waves x 16 q-rows
// (LDS still 80KB -> 2 blocks/CU -> 4 waves/SIMD, was 2). Row-sum l moved off the
// MFMA pipe (was 11% of MFMA ops) into f32 VALU accumulate + epilogue shfl reduce.
// s_setprio(1) around MFMA clusters (T5). Goal: overlap exp-VALU with MFMA.

#define SEQ 4096
#define DIM 1024
#define NH 16
#define HD 64

typedef unsigned short u16;
typedef __attribute__((ext_vector_type(4))) u16 u16x4;
typedef __attribute__((ext_vector_type(8))) short s16x8;   // MFMA a/b operand (8 bf16)
typedef __attribute__((ext_vector_type(4))) float f32x4;   // MFMA c/d operand
typedef __attribute__((ext_vector_type(2))) unsigned u32x2;

static __device__ __forceinline__ u16 f2bf(float f) {
  unsigned u = __builtin_bit_cast(unsigned, f);
  u += 0x7FFF + ((u >> 16) & 1);   // RNE
  return (u16)(u >> 16);
}

static __device__ __forceinline__ void glds16(const u16* g, u16* l) {
  __builtin_amdgcn_global_load_lds((const __attribute__((address_space(1))) unsigned*)g,
                                   (__attribute__((address_space(3))) unsigned*)l, 16, 0, 0);
}

static __device__ __forceinline__ float fast_exp2(float x) {
#if __has_builtin(__builtin_amdgcn_exp2f)
  return __builtin_amdgcn_exp2f(x);
#else
  return exp2f(x);
#endif
}

// pack bf16(lo=p0, hi=p1) via byte-perm (RTZ truncation)
static __device__ __forceinline__ unsigned pack_bf(float p0, float p1) {
  return __builtin_amdgcn_perm(__builtin_bit_cast(unsigned, p1),
                               __builtin_bit_cast(unsigned, p0), 0x07060302u);
}

// ---------------- kernel 1: fused RoPE-cast + weight convert ----------------
__global__ __launch_bounds__(256) void prep(const float* __restrict__ x,
                                            const float* __restrict__ cs,
                                            const float* __restrict__ sn,
                                            const float* __restrict__ Wq,
                                            const float* __restrict__ Wk,
                                            const float* __restrict__ Wv,
                                            const float* __restrict__ Wo,
                                            u16* __restrict__ Xr,
                                            u16* __restrict__ Wb) {
  int b = blockIdx.x;
  if (b < 4096) {
    int idx = (b * 256 + threadIdx.x) * 4;
    int d = idx & (DIM - 1);
    f32x4 xv = *(const f32x4*)&x[idx];
    f32x4 cv = *(const f32x4*)&cs[idx];
    f32x4 sv = *(const f32x4*)&sn[idx];
    f32x4 rv;
    if (d < DIM / 2) rv = -*(const f32x4*)&x[idx + DIM / 2];
    else             rv =  *(const f32x4*)&x[idx - DIM / 2];
    f32x4 o = xv * cv + rv * sv;
    u16x4 ov;
    for (int i = 0; i < 4; i++) ov[i] = f2bf(o[i]);
    *(u16x4*)&Xr[idx] = ov;
  } else {
    int idx = ((b - 4096) * 256 + threadIdx.x) * 4;
    const int M = 1 << 20;
    const float* src = (idx < M) ? Wq : (idx < 2 * M) ? Wk : (idx < 3 * M) ? Wv : Wo;
    int off = idx & (M - 1);
    f32x4 v = *(const f32x4*)&src[off];
    u16x4 ov;
    for (int i = 0; i < 4; i++) ov[i] = f2bf(v[i]);
    *(u16x4*)&Wb[idx] = ov;
  }
}

// ---------------- kernel 2: QKV GEMM (C = A @ W^T + b), BK32 dbuf ----------------
__global__ __launch_bounds__(256) void qkv_gemm(const u16* __restrict__ Xr,
                                                const u16* __restrict__ Wb,
                                                const float* __restrict__ bq,
                                                const float* __restrict__ bk,
                                                const float* __restrict__ bv,
                                                u16* __restrict__ Qo,
                                                u16* __restrict__ Ko,
                                                u16* __restrict__ Vt) {
  const int z = blockIdx.z;
  const u16* W = Wb + (size_t)z * DIM * DIM;
  const float* bias = (z == 0) ? bq : (z == 1) ? bk : bv;
  const float scale = (z == 0) ? 0.180336884f : 1.0f;   // 0.125 * log2(e) for Q

  const int m0 = blockIdx.x * 128, n0 = blockIdx.y * 128;
  const int tid = threadIdx.x;
  const int w = tid >> 6, lane = tid & 63, quad = lane >> 4, ln = lane & 15;
  const int rowoff = (w >> 1) * 64, coloff = (w & 1) * 64;

  __shared__ __align__(16) u16 As[2][128 * 32];
  __shared__ __align__(16) u16 Bs[2][128 * 32];

  f32x4 acc[4][4];
  for (int i = 0; i < 4; i++)
    for (int j = 0; j < 4; j++) acc[i][j] = (f32x4){0.f, 0.f, 0.f, 0.f};

  for (int t = 0; t < 2; t++) {
    int i = tid + t * 256, r = i >> 2, p = i & 3, cc = (p ^ (r & 3)) * 8;
    glds16(&Xr[(size_t)(m0 + r) * DIM + cc], As[0] + i * 8);
    glds16(&W[(size_t)(n0 + r) * DIM + cc], Bs[0] + i * 8);
  }

  for (int kt = 0; kt < 32; kt++) {
    __syncthreads();
    if (kt < 31) {
      int k0 = (kt + 1) * 32, nb = (kt + 1) & 1;
      for (int t = 0; t < 2; t++) {
        int i = tid + t * 256, r = i >> 2, p = i & 3, cc = (p ^ (r & 3)) * 8;
        glds16(&Xr[(size_t)(m0 + r) * DIM + k0 + cc], As[nb] + i * 8);
        glds16(&W[(size_t)(n0 + r) * DIM + k0 + cc], Bs[nb] + i * 8);
      }
    }
    int bb = kt & 1;
    s16x8 af[4], bf[4];
    for (int i = 0; i < 4; i++)
      af[i] = *(const s16x8*)&As[bb][(rowoff + i * 16 + ln) * 32 + ((quad ^ (ln & 3)) * 8)];
    for (int j = 0; j < 4; j++)
      bf[j] = *(const s16x8*)&Bs[bb][(coloff + j * 16 + ln) * 32 + ((quad ^ (ln & 3)) * 8)];
    for (int i = 0; i < 4; i++)
      for (int j = 0; j < 4; j++)
        acc[i][j] = __builtin_amdgcn_mfma_f32_16x16x32_bf16(af[i], bf[j], acc[i][j], 0, 0, 0);
  }

  if (z < 2) {
    u16* out = (z == 0) ? Qo : Ko;
    for (int i = 0; i < 4; i++)
      for (int j = 0; j < 4; j++)
        for (int r = 0; r < 4; r++) {
          int row = m0 + rowoff + i * 16 + quad * 4 + r;
          int col = n0 + coloff + j * 16 + ln;
          out[(size_t)row * DIM + col] = f2bf((acc[i][j][r] + bias[col]) * scale);
        }
  } else {
    for (int i = 0; i < 4; i++)
      for (int j = 0; j < 4; j++) {
        int row0 = m0 + rowoff + i * 16 + quad * 4;
        int col = n0 + coloff + j * 16 + ln;
        u16x4 pk;
        for (int r = 0; r < 4; r++) pk[r] = f2bf(acc[i][j][r] + bias[col]);
        *(u16x4*)&Vt[(size_t)col * SEQ + row0] = pk;
      }
  }
}

// ---------------- kernel 3: flash attention, 8-wave blocks (4 waves/SIMD) ----------------
// block = (head, 128 q rows); 8 waves x 16 q rows; kv tiles 64, 2 slots/round,
// slot-pipelined (S-MFMAs of slot1 hide slot0's P write->read LDS latency).
// Row sum accumulated on VALU during exp phase (no l-MFMA); epilogue shfl reduce.
__global__ __launch_bounds__(512, 4) void attn_kernel(const u16* __restrict__ Q,
                                                      const u16* __restrict__ K,
                                                      const u16* __restrict__ Vt,
                                                      u16* __restrict__ attn) {
  const int b = blockIdx.x;
  const int h = (b & 7) * 2 + ((b >> 3) & 1);   // XCD-aware: 2 heads per XCD
  const int q0 = (b >> 4) * 128;
  const int tid = threadIdx.x;
  const int w = tid >> 6, lane = tid & 63, quad = lane >> 4, ln = lane & 15;

  __shared__ __align__(16) u16 QP[128 * 64];        // 16K: Q at start, then per-wave P
  __shared__ __align__(16) u16 Ks[2][2][64 * 64];   // 32K [buf][slot], XOR swizzled
  __shared__ __align__(16) u16 Vts[2][2][64 * 64];  // 32K [buf][slot], [d][kv] swizzled

  // stage Q (128x64): 1024 16B chunks over 512 threads
  for (int t = 0; t < 2; t++) {
    int i = tid + t * 512, r = i >> 3, p = i & 7, cc = (p ^ (r & 7)) * 8;
    glds16(&Q[(size_t)(q0 + r) * DIM + h * HD + cc], QP + i * 8);
  }
  const int sr = tid >> 3, pos = tid & 7;       // sr in 0..63: full kv-tile row
  const int cc = (pos ^ (sr & 7)) * 8;
  const u16* Kg = &K[(size_t)sr * DIM + h * HD + cc];
  const u16* Vg = &Vt[(size_t)(h * HD + sr) * SEQ + cc];

  for (int t = 0; t < 2; t++) {   // prologue: tiles 0,1 -> buf 0
    glds16(Kg + (size_t)t * 64 * DIM, Ks[0][t] + tid * 8);
    glds16(Vg + t * 64, Vts[0][t] + tid * 8);
  }
  __syncthreads();

  // Q fragments, loop-invariant (read before first loop barrier)
  s16x8 qf[2];
  for (int hh = 0; hh < 2; hh++)
    qf[hh] = *(const s16x8*)&QP[(w * 16 + ln) * 64 + (((hh * 4 + quad) ^ (ln & 7)) * 8)];

  f32x4 o[4];
  f32x4 lsum = (f32x4){0.f, 0.f, 0.f, 0.f};
  for (int n = 0; n < 4; n++) o[n] = (f32x4){0.f, 0.f, 0.f, 0.f};

  u16* Pw = QP + w * (16 * 64);       // per-wave P strip (16 rows x 64 kv)
  const float EC = -23.0831206542f;   // -16*log2(e), as MFMA C-init

  for (int rnd = 0; rnd < 32; rnd++) {
    __syncthreads();     // drains this round's tiles (issued one round ago)
    if (rnd < 31) {      // prefetch next 2 tiles into other buffer
      int nb = (rnd + 1) & 1;
      size_t kt = (size_t)(rnd + 1) * 2;
      for (int t = 0; t < 2; t++) {
        glds16(Kg + (kt + t) * 64 * DIM, Ks[nb][t] + tid * 8);
        glds16(Vg + (kt + t) * 64, Vts[nb][t] + tid * 8);
      }
    }
    const int bb = rnd & 1;
    const u16* K0 = Ks[bb][0];  const u16* V0 = Vts[bb][0];
    const u16* K1 = Ks[bb][1];  const u16* V1 = Vts[bb][1];

    // ---- phase A: S^T slot0 ----
    f32x4 St0[4];
    __builtin_amdgcn_s_setprio(1);
    for (int c = 0; c < 4; c++) {
      int rr = c * 16 + ln;
      s16x8 kf0 = *(const s16x8*)&K0[rr * 64 + ((quad ^ (ln & 7)) * 8)];
      s16x8 kf1 = *(const s16x8*)&K0[rr * 64 + (((4 + quad) ^ (ln & 7)) * 8)];
      f32x4 t = (f32x4){EC, EC, EC, EC};
      t = __builtin_amdgcn_mfma_f32_16x16x32_bf16(kf0, qf[0], t, 0, 0, 0);
      t = __builtin_amdgcn_mfma_f32_16x16x32_bf16(kf1, qf[1], t, 0, 0, 0);
      St0[c] = t;
    }
    __builtin_amdgcn_s_setprio(0);
    // ---- phase B: exp/pack/P-write slot0 (+ VALU row-sum) ----
    for (int c = 0; c < 4; c++) {
      f32x4 p;
      for (int r = 0; r < 4; r++) p[r] = fast_exp2(St0[c][r]);
      lsum += p;
      u32x2 pk;
      pk[0] = pack_bf(p[0], p[1]);
      pk[1] = pack_bf(p[2], p[3]);
      *(u32x2*)&Pw[ln * 64 + (((c * 2 + (quad >> 1)) ^ (ln & 7)) * 8) + (quad & 1) * 4] = pk;
    }
    // ---- phase C: S^T slot1 (hides slot0's P write->read latency) ----
    f32x4 St1[4];
    __builtin_amdgcn_s_setprio(1);
    for (int c = 0; c < 4; c++) {
      int rr = c * 16 + ln;
      s16x8 kf0 = *(const s16x8*)&K1[rr * 64 + ((quad ^ (ln & 7)) * 8)];
      s16x8 kf1 = *(const s16x8*)&K1[rr * 64 + (((4 + quad) ^ (ln & 7)) * 8)];
      f32x4 t = (f32x4){EC, EC, EC, EC};
      t = __builtin_amdgcn_mfma_f32_16x16x32_bf16(kf0, qf[0], t, 0, 0, 0);
      t = __builtin_amdgcn_mfma_f32_16x16x32_bf16(kf1, qf[1], t, 0, 0, 0);
      St1[c] = t;
    }
    __builtin_amdgcn_s_setprio(0);
    // ---- phase D: P-read + PV slot0 ----
    {
      s16x8 pf0 = *(const s16x8*)&Pw[ln * 64 + ((quad ^ (ln & 7)) * 8)];
      s16x8 pf1 = *(const s16x8*)&Pw[ln * 64 + (((4 + quad) ^ (ln & 7)) * 8)];
      __builtin_amdgcn_s_setprio(1);
      for (int n = 0; n < 4; n++) {
        int rr = n * 16 + ln;
        s16x8 vf0 = *(const s16x8*)&V0[rr * 64 + ((quad ^ (ln & 7)) * 8)];
        s16x8 vf1 = *(const s16x8*)&V0[rr * 64 + (((4 + quad) ^ (ln & 7)) * 8)];
        o[n] = __builtin_amdgcn_mfma_f32_16x16x32_bf16(pf0, vf0, o[n], 0, 0, 0);
        o[n] = __builtin_amdgcn_mfma_f32_16x16x32_bf16(pf1, vf1, o[n], 0, 0, 0);
      }
      __builtin_amdgcn_s_setprio(0);
    }
    // ---- phase E: exp/pack/P-write slot1 (DS ops in-order after phase-D reads) ----
    for (int c = 0; c < 4; c++) {
      f32x4 p;
      for (int r = 0; r < 4; r++) p[r] = fast_exp2(St1[c][r]);
      lsum += p;
      u32x2 pk;
      pk[0] = pack_bf(p[0], p[1]);
      pk[1] = pack_bf(p[2], p[3]);
      *(u32x2*)&Pw[ln * 64 + (((c * 2 + (quad >> 1)) ^ (ln & 7)) * 8) + (quad & 1) * 4] = pk;
    }
    // ---- phase F: P-read + PV slot1 ----
    {
      s16x8 pf0 = *(const s16x8*)&Pw[ln * 64 + ((quad ^ (ln & 7)) * 8)];
      s16x8 pf1 = *(const s16x8*)&Pw[ln * 64 + (((4 + quad) ^ (ln & 7)) * 8)];
      __builtin_amdgcn_s_setprio(1);
      for (int n = 0; n < 4; n++) {
        int rr = n * 16 + ln;
        s16x8 vf0 = *(const s16x8*)&V1[rr * 64 + ((quad ^ (ln & 7)) * 8)];
        s16x8 vf1 = *(const s16x8*)&V1[rr * 64 + (((4 + quad) ^ (ln & 7)) * 8)];
        o[n] = __builtin_amdgcn_mfma_f32_16x16x32_bf16(pf0, vf0, o[n], 0, 0, 0);
        o[n] = __builtin_amdgcn_mfma_f32_16x16x32_bf16(pf1, vf1, o[n], 0, 0, 0);
      }
      __builtin_amdgcn_s_setprio(0);
    }
  }

  // epilogue: reduce lsum across quads (lanes ln, ln+16, ln+32, ln+48 hold
  // disjoint kv chunks of q-row w*16+ln), then fetch per-output-row inverse.
  float ls = lsum[0] + lsum[1] + lsum[2] + lsum[3];
  ls += __shfl_xor(ls, 16, 64);
  ls += __shfl_xor(ls, 32, 64);
  for (int r = 0; r < 4; r++) {
    float lv = __shfl(ls, quad * 4 + r, 64);   // lane (quad*4+r) holds that row's sum
    float inv = __builtin_amdgcn_rcpf(lv);
    int row = q0 + w * 16 + quad * 4 + r;
    for (int n = 0; n < 4; n++)
      attn[(size_t)row * DIM + h * HD + n * 16 + ln] = f2bf(o[n][r] * inv);
  }
}

// ---------------- kernel 4: output GEMM + bias + residual (fp32 out), 128x128 BK32 ----------------
__global__ __launch_bounds__(256) void out_gemm(const u16* __restrict__ A,
                                                const u16* __restrict__ W,
                                                const float* __restrict__ bo,
                                                const float* __restrict__ resid,
                                                float* __restrict__ out) {
  const int m0 = blockIdx.x * 128, n0 = blockIdx.y * 128;
  const int tid = threadIdx.x;
  const int w = tid >> 6, lane = tid & 63, quad = lane >> 4, ln = lane & 15;
  const int rowoff = (w >> 1) * 64, coloff = (w & 1) * 64;

  __shared__ __align__(16) u16 As[2][128 * 32];
  __shared__ __align__(16) u16 Bs[2][128 * 32];

  f32x4 acc[4][4];
  for (int i = 0; i < 4; i++)
    for (int j = 0; j < 4; j++) acc[i][j] = (f32x4){0.f, 0.f, 0.f, 0.f};

  for (int t = 0; t < 2; t++) {
    int i = tid + t * 256, r = i >> 2, p = i & 3, cc = (p ^ (r & 3)) * 8;
    glds16(&A[(size_t)(m0 + r) * DIM + cc], As[0] + i * 8);
    glds16(&W[(size_t)(n0 + r) * DIM + cc], Bs[0] + i * 8);
  }

  for (int kt = 0; kt < 32; kt++) {
    __syncthreads();
    if (kt < 31) {
      int k0 = (kt + 1) * 32, nb = (kt + 1) & 1;
      for (int t = 0; t < 2; t++) {
        int i = tid + t * 256, r = i >> 2, p = i & 3, cc = (p ^ (r & 3)) * 8;
        glds16(&A[(size_t)(m0 + r) * DIM + k0 + cc], As[nb] + i * 8);
        glds16(&W[(size_t)(n0 + r) * DIM + k0 + cc], Bs[nb] + i * 8);
      }
    }
    int bb = kt & 1;
    s16x8 af[4], bf[4];
    for (int i = 0; i < 4; i++)
      af[i] = *(const s16x8*)&As[bb][(rowoff + i * 16 + ln) * 32 + ((quad ^ (ln & 3)) * 8)];
    for (int j = 0; j < 4; j++)
      bf[j] = *(const s16x8*)&Bs[bb][(coloff + j * 16 + ln) * 32 + ((quad ^ (ln & 3)) * 8)];
    for (int i = 0; i < 4; i++)
      for (int j = 0; j < 4; j++)
        acc[i][j] = __builtin_amdgcn_mfma_f32_16x16x32_bf16(af[i], bf[j], acc[i][j], 0, 0, 0);
  }

  for (int i = 0; i < 4; i++)
    for (int j = 0; j < 4; j++)
      for (int r = 0; r < 4; r++) {
        int row = m0 + rowoff + i * 16 + quad * 4 + r;
        int col = n0 + coloff + j * 16 + ln;
        out[(size_t)row * DIM + col] = acc[i][j][r] + bo[col] + resid[(size_t)row * DIM + col];
      }
}

// ---------------- launch ----------------
extern "C" void kernel_launch(void* const* d_in, const int* in_sizes, int n_in,
                              void* d_out, int out_size, void* d_ws, size_t ws_size,
                              hipStream_t stream) {
  const float* cs = (const float*)d_in[0];
  const float* sn = (const float*)d_in[1];
  const float* x  = (const float*)d_in[2];
  const float* Wq = (const float*)d_in[4];  const float* bq = (const float*)d_in[5];
  const float* Wk = (const float*)d_in[6];  const float* bk = (const float*)d_in[7];
  const float* Wv = (const float*)d_in[8];  const float* bv = (const float*)d_in[9];
  const float* Wo = (const float*)d_in[10]; const float* bo = (const float*)d_in[11];
  float* out = (float*)d_out;

  char* ws = (char*)d_ws;
  u16* Xr = (u16*)(ws + (size_t)0);
  u16* Wb = (u16*)(ws + ((size_t)8 << 20));
  u16* Qb = (u16*)(ws + ((size_t)16 << 20));
  u16* Kb = (u16*)(ws + ((size_t)24 << 20));
  u16* Vt = (u16*)(ws + ((size_t)32 << 20));
  u16* Ab = (u16*)(ws + ((size_t)40 << 20));

  prep<<<8192, 256, 0, stream>>>(x, cs, sn, Wq, Wk, Wv, Wo, Xr, Wb);
  qkv_gemm<<<dim3(32, 8, 3), 256, 0, stream>>>(Xr, Wb, bq, bk, bv, Qb, Kb, Vt);
  attn_kernel<<<512, 512, 0, stream>>>(Qb, Kb, Vt, Ab);
  out_gemm<<<dim3(32, 8), 256, 0, stream>>>(Ab, Wb + ((size_t)3 << 20), bo, x, out);
}

// Round 2
// 265.657 us; speedup vs baseline: 1.0288x; 1.0288x over previous
//
#include <hip/hip_runtime.h>
#include <hip/hip_bf16.h>

// AttentionBlock: S=4096, D=1024, H=16, hd=64. fp32 in/out, bf16 MFMA internally.
// ws layout (48 MB):
//   [ 0, 8)MB  Xr : RoPE'd input, bf16 [4096][1024]
//   [ 8,16)MB  Wb : Wq|Wk|Wv|Wo bf16, each [1024][1024] (N x K row-major)
//   [16,24)MB  Q  : bf16 [4096][1024] (pre-scaled by 0.125*log2(e))
//   [24,32)MB  K  : bf16 [4096][1024]
//   [32,40)MB  Vt : bf16 [1024][4096]  == V^T  (row = h*64+d, col = seq)
//   [40,48)MB  Ab : attn out bf16 [4096][1024]
// Softmax: fixed-max. p = exp2(S - 16*log2e) with 0.125*log2e folded into Q.
// Round 8: attn was LDS-BW-bound (R7: 68 TB/s ~ 98% of 69 TB/s ceiling; occupancy
// doubling was a no-op). Restructure: 32x32x16 MFMAs, 32 q-rows/wave (halves K/V
// LDS reads per FLOP), and P kept ENTIRELY in registers via pack_bf +
// v_permlane32_swap_b32 (T12 -- VALU pipe, zero LDS). LDS 64KB (Q staged into
// round-1 K buffer). Per-CU-round b128 reads: 576 -> 256.

#define SEQ 4096
#define DIM 1024
#define NH 16
#define HD 64

typedef unsigned short u16;
typedef __attribute__((ext_vector_type(4))) u16 u16x4;
typedef __attribute__((ext_vector_type(8))) short s16x8;    // MFMA a/b operand (8 bf16)
typedef __attribute__((ext_vector_type(4))) float f32x4;    // MFMA c/d operand (16x16)
typedef __attribute__((ext_vector_type(16))) float f32x16;  // MFMA c/d operand (32x32)
typedef __attribute__((ext_vector_type(4))) unsigned u32x4;

static __device__ __forceinline__ u16 f2bf(float f) {
  unsigned u = __builtin_bit_cast(unsigned, f);
  u += 0x7FFF + ((u >> 16) & 1);   // RNE
  return (u16)(u >> 16);
}

static __device__ __forceinline__ void glds16(const u16* g, u16* l) {
  __builtin_amdgcn_global_load_lds((const __attribute__((address_space(1))) unsigned*)g,
                                   (__attribute__((address_space(3))) unsigned*)l, 16, 0, 0);
}

static __device__ __forceinline__ float fast_exp2(float x) {
#if __has_builtin(__builtin_amdgcn_exp2f)
  return __builtin_amdgcn_exp2f(x);
#else
  return exp2f(x);
#endif
}

// pack bf16(lo=p0, hi=p1) via byte-perm (RTZ truncation)
static __device__ __forceinline__ unsigned pack_bf(float p0, float p1) {
  return __builtin_amdgcn_perm(__builtin_bit_cast(unsigned, p1),
                               __builtin_bit_cast(unsigned, p0), 0x07060302u);
}

// ---------------- kernel 1: fused RoPE-cast + weight convert ----------------
__global__ __launch_bounds__(256) void prep(const float* __restrict__ x,
                                            const float* __restrict__ cs,
                                            const float* __restrict__ sn,
                                            const float* __restrict__ Wq,
                                            const float* __restrict__ Wk,
                                            const float* __restrict__ Wv,
                                            const float* __restrict__ Wo,
                                            u16* __restrict__ Xr,
                                            u16* __restrict__ Wb) {
  int b = blockIdx.x;
  if (b < 4096) {
    int idx = (b * 256 + threadIdx.x) * 4;
    int d = idx & (DIM - 1);
    f32x4 xv = *(const f32x4*)&x[idx];
    f32x4 cv = *(const f32x4*)&cs[idx];
    f32x4 sv = *(const f32x4*)&sn[idx];
    f32x4 rv;
    if (d < DIM / 2) rv = -*(const f32x4*)&x[idx + DIM / 2];
    else             rv =  *(const f32x4*)&x[idx - DIM / 2];
    f32x4 o = xv * cv + rv * sv;
    u16x4 ov;
    for (int i = 0; i < 4; i++) ov[i] = f2bf(o[i]);
    *(u16x4*)&Xr[idx] = ov;
  } else {
    int idx = ((b - 4096) * 256 + threadIdx.x) * 4;
    const int M = 1 << 20;
    const float* src = (idx < M) ? Wq : (idx < 2 * M) ? Wk : (idx < 3 * M) ? Wv : Wo;
    int off = idx & (M - 1);
    f32x4 v = *(const f32x4*)&src[off];
    u16x4 ov;
    for (int i = 0; i < 4; i++) ov[i] = f2bf(v[i]);
    *(u16x4*)&Wb[idx] = ov;
  }
}

// ---------------- kernel 2: QKV GEMM (C = A @ W^T + b), BK32 dbuf ----------------
__global__ __launch_bounds__(256) void qkv_gemm(const u16* __restrict__ Xr,
                                                const u16* __restrict__ Wb,
                                                const float* __restrict__ bq,
                                                const float* __restrict__ bk,
                                                const float* __restrict__ bv,
                                                u16* __restrict__ Qo,
                                                u16* __restrict__ Ko,
                                                u16* __restrict__ Vt) {
  const int z = blockIdx.z;
  const u16* W = Wb + (size_t)z * DIM * DIM;
  const float* bias = (z == 0) ? bq : (z == 1) ? bk : bv;
  const float scale = (z == 0) ? 0.180336884f : 1.0f;   // 0.125 * log2(e) for Q

  const int m0 = blockIdx.x * 128, n0 = blockIdx.y * 128;
  const int tid = threadIdx.x;
  const int w = tid >> 6, lane = tid & 63, quad = lane >> 4, ln = lane & 15;
  const int rowoff = (w >> 1) * 64, coloff = (w & 1) * 64;

  __shared__ __align__(16) u16 As[2][128 * 32];
  __shared__ __align__(16) u16 Bs[2][128 * 32];

  f32x4 acc[4][4];
  for (int i = 0; i < 4; i++)
    for (int j = 0; j < 4; j++) acc[i][j] = (f32x4){0.f, 0.f, 0.f, 0.f};

  for (int t = 0; t < 2; t++) {
    int i = tid + t * 256, r = i >> 2, p = i & 3, cc = (p ^ (r & 3)) * 8;
    glds16(&Xr[(size_t)(m0 + r) * DIM + cc], As[0] + i * 8);
    glds16(&W[(size_t)(n0 + r) * DIM + cc], Bs[0] + i * 8);
  }

  for (int kt = 0; kt < 32; kt++) {
    __syncthreads();
    if (kt < 31) {
      int k0 = (kt + 1) * 32, nb = (kt + 1) & 1;
      for (int t = 0; t < 2; t++) {
        int i = tid + t * 256, r = i >> 2, p = i & 3, cc = (p ^ (r & 3)) * 8;
        glds16(&Xr[(size_t)(m0 + r) * DIM + k0 + cc], As[nb] + i * 8);
        glds16(&W[(size_t)(n0 + r) * DIM + k0 + cc], Bs[nb] + i * 8);
      }
    }
    int bb = kt & 1;
    s16x8 af[4], bf[4];
    for (int i = 0; i < 4; i++)
      af[i] = *(const s16x8*)&As[bb][(rowoff + i * 16 + ln) * 32 + ((quad ^ (ln & 3)) * 8)];
    for (int j = 0; j < 4; j++)
      bf[j] = *(const s16x8*)&Bs[bb][(coloff + j * 16 + ln) * 32 + ((quad ^ (ln & 3)) * 8)];
    for (int i = 0; i < 4; i++)
      for (int j = 0; j < 4; j++)
        acc[i][j] = __builtin_amdgcn_mfma_f32_16x16x32_bf16(af[i], bf[j], acc[i][j], 0, 0, 0);
  }

  if (z < 2) {
    u16* out = (z == 0) ? Qo : Ko;
    for (int i = 0; i < 4; i++)
      for (int j = 0; j < 4; j++)
        for (int r = 0; r < 4; r++) {
          int row = m0 + rowoff + i * 16 + quad * 4 + r;
          int col = n0 + coloff + j * 16 + ln;
          out[(size_t)row * DIM + col] = f2bf((acc[i][j][r] + bias[col]) * scale);
        }
  } else {
    for (int i = 0; i < 4; i++)
      for (int j = 0; j < 4; j++) {
        int row0 = m0 + rowoff + i * 16 + quad * 4;
        int col = n0 + coloff + j * 16 + ln;
        u16x4 pk;
        for (int r = 0; r < 4; r++) pk[r] = f2bf(acc[i][j][r] + bias[col]);
        *(u16x4*)&Vt[(size_t)col * SEQ + row0] = pk;
      }
  }
}

// ---------------- kernel 3: flash attention, 32x32 MFMA, register-resident P ----------------
// block = (head, 128 q rows); 4 waves x 32 q rows. kv tiles 64, 2 slots/round.
// S^T = mfma32(K, Q): lane holds P^T[kv subset][q = l&31]. exp+pack+permlane32_swap
// rebuilds the PV A-operand fragment entirely in registers (no P LDS round-trip).
__global__ __launch_bounds__(256, 2) void attn_kernel(const u16* __restrict__ Q,
                                                      const u16* __restrict__ K,
                                                      const u16* __restrict__ Vt,
                                                      u16* __restrict__ attn) {
  const int b = blockIdx.x;
  const int h = (b & 7) * 2 + ((b >> 3) & 1);   // XCD-aware: 2 heads per XCD
  const int q0 = (b >> 4) * 128;
  const int tid = threadIdx.x;
  const int w = tid >> 6, lane = tid & 63;
  const int l31 = lane & 31, hi = lane >> 5;
  const int e3 = l31 & 7;

  __shared__ __align__(16) u16 Ks[2][2][64 * 64];   // 32K [buf][slot]; Ks[1] doubles as Q stage
  __shared__ __align__(16) u16 Vts[2][2][64 * 64];  // 32K [buf][slot], [d][kv]

  // stage Q (128x64) into Ks[1] region (freed before round 0 prefetches into it)
  u16* QP = &Ks[1][0][0];
  for (int t = 0; t < 4; t++) {
    int i = tid + t * 256, r = i >> 3, p = i & 7, cc = (p ^ (r & 7)) * 8;
    glds16(&Q[(size_t)(q0 + r) * DIM + h * HD + cc], QP + i * 8);
  }
  // K/V tile staging pointers (rows sr and sr+32; (sr+32)&7 == sr&7 so same cc)
  const int sr = tid >> 3, pos = tid & 7;
  const int cc = (pos ^ (sr & 7)) * 8;
  const u16* Kg0 = &K[(size_t)sr * DIM + h * HD + cc];
  const u16* Kg1 = &K[(size_t)(sr + 32) * DIM + h * HD + cc];
  const u16* Vg0 = &Vt[(size_t)(h * HD + sr) * SEQ + cc];
  const u16* Vg1 = &Vt[(size_t)(h * HD + sr + 32) * SEQ + cc];

  for (int t = 0; t < 2; t++) {   // prologue: tiles 0,1 -> buf 0
    glds16(Kg0 + (size_t)t * 64 * DIM, Ks[0][t] + tid * 8);
    glds16(Kg1 + (size_t)t * 64 * DIM, Ks[0][t] + (tid + 256) * 8);
    glds16(Vg0 + t * 64, Vts[0][t] + tid * 8);
    glds16(Vg1 + t * 64, Vts[0][t] + (tid + 256) * 8);
  }
  __syncthreads();

  // Q B-fragments (loop-invariant): lane holds Q[q = w*32+l31][k = step*16 + hi*8 + 0..7]
  s16x8 qf[4];
  {
    int qrow = w * 32 + l31;
#pragma unroll
    for (int s = 0; s < 4; s++)
      qf[s] = *(const s16x8*)&QP[qrow * 64 + (((s * 2 + hi) ^ (qrow & 7)) * 8)];
  }

  f32x16 o[2];
#pragma unroll
  for (int db = 0; db < 2; db++)
#pragma unroll
    for (int i = 0; i < 16; i++) o[db][i] = 0.f;
  float lsum = 0.f;
  const float EC = -23.0831206542f;   // -16*log2(e), as MFMA C-init

  for (int rnd = 0; rnd < 32; rnd++) {
    __syncthreads();     // drains this round's tiles + (rnd 0) guards Q-region reuse
    if (rnd < 31) {      // prefetch next 2 tiles into other buffer
      int nb = (rnd + 1) & 1;
      size_t kt = (size_t)(rnd + 1) * 2;
#pragma unroll
      for (int t = 0; t < 2; t++) {
        glds16(Kg0 + (kt + t) * 64 * DIM, Ks[nb][t] + tid * 8);
        glds16(Kg1 + (kt + t) * 64 * DIM, Ks[nb][t] + (tid + 256) * 8);
        glds16(Vg0 + (kt + t) * 64, Vts[nb][t] + tid * 8);
        glds16(Vg1 + (kt + t) * 64, Vts[nb][t] + (tid + 256) * 8);
      }
    }
    const int bb = rnd & 1;
#pragma unroll
    for (int slot = 0; slot < 2; slot++) {
      const u16* Kt = Ks[bb][slot];
      const u16* Vv = Vts[bb][slot];

      // ---- S^T = K-tile x Q^T (2 kv-blocks x 4 k-steps of 32x32x16) ----
      f32x16 St[2];
#pragma unroll
      for (int kb = 0; kb < 2; kb++)
#pragma unroll
        for (int i = 0; i < 16; i++) St[kb][i] = EC;
      __builtin_amdgcn_s_setprio(1);
#pragma unroll
      for (int s = 0; s < 4; s++)
#pragma unroll
        for (int kb = 0; kb < 2; kb++) {
          int row = kb * 32 + l31;
          s16x8 kf = *(const s16x8*)&Kt[row * 64 + (((s * 2 + hi) ^ e3) * 8)];
          St[kb] = __builtin_amdgcn_mfma_f32_32x32x16_bf16(kf, qf[s], St[kb], 0, 0, 0);
        }
      __builtin_amdgcn_s_setprio(0);

      // ---- exp + pack + permlane32_swap -> PA[4] (register-only P) ----
      // St reg r of block kb: P^T[kv = kb*32 + (r&3)+8*(r>>2)+4*hi][q = l31].
      // PA[step] = A-operand P[q = l31][kv = step*16 + hi*8 + 0..7].
      s16x8 PA[4];
#pragma unroll
      for (int hf = 0; hf < 4; hf++) {
        int kb = hf >> 1, s0 = (hf & 1) * 8;
        float p[8];
#pragma unroll
        for (int m = 0; m < 8; m++) {
          p[m] = fast_exp2(St[kb][s0 + m]);
          lsum += p[m];
        }
        unsigned A = pack_bf(p[0], p[1]);
        unsigned B = pack_bf(p[4], p[5]);
        unsigned C = pack_bf(p[2], p[3]);
        unsigned D = pack_bf(p[6], p[7]);
        asm volatile("v_permlane32_swap_b32 %0, %1" : "+v"(A), "+v"(B));
        asm volatile("v_permlane32_swap_b32 %0, %1" : "+v"(C), "+v"(D));
        u32x4 wd = {A, C, B, D};
        PA[hf] = __builtin_bit_cast(s16x8, wd);
      }

      // ---- PV: O += P x V (2 d-blocks x 4 kv-steps of 32x32x16) ----
      __builtin_amdgcn_s_setprio(1);
#pragma unroll
      for (int s = 0; s < 4; s++)
#pragma unroll
        for (int db = 0; db < 2; db++) {
          int row = db * 32 + l31;
          s16x8 vf = *(const s16x8*)&Vv[row * 64 + (((s * 2 + hi) ^ e3) * 8)];
          o[db] = __builtin_amdgcn_mfma_f32_32x32x16_bf16(PA[s], vf, o[db], 0, 0, 0);
        }
      __builtin_amdgcn_s_setprio(0);
    }
  }

  // epilogue: lane's lsum covers its kv half for q = l31; other half has the rest.
  lsum += __shfl_xor(lsum, 32, 64);
  float inv = __builtin_amdgcn_rcpf(lsum);
#pragma unroll
  for (int r = 0; r < 16; r++) {
    int qr = (r & 3) + 8 * (r >> 2) + 4 * hi;
    float iv = __shfl(inv, qr, 64);   // lane qr holds the row-sum for q row qr
    int row = q0 + w * 32 + qr;
#pragma unroll
    for (int db = 0; db < 2; db++)
      attn[(size_t)row * DIM + h * HD + db * 32 + l31] = f2bf(o[db][r] * iv);
  }
}

// ---------------- kernel 4: output GEMM + bias + residual (fp32 out), 128x128 BK32 ----------------
__global__ __launch_bounds__(256) void out_gemm(const u16* __restrict__ A,
                                                const u16* __restrict__ W,
                                                const float* __restrict__ bo,
                                                const float* __restrict__ resid,
                                                float* __restrict__ out) {
  const int m0 = blockIdx.x * 128, n0 = blockIdx.y * 128;
  const int tid = threadIdx.x;
  const int w = tid >> 6, lane = tid & 63, quad = lane >> 4, ln = lane & 15;
  const int rowoff = (w >> 1) * 64, coloff = (w & 1) * 64;

  __shared__ __align__(16) u16 As[2][128 * 32];
  __shared__ __align__(16) u16 Bs[2][128 * 32];

  f32x4 acc[4][4];
  for (int i = 0; i < 4; i++)
    for (int j = 0; j < 4; j++) acc[i][j] = (f32x4){0.f, 0.f, 0.f, 0.f};

  for (int t = 0; t < 2; t++) {
    int i = tid + t * 256, r = i >> 2, p = i & 3, cc = (p ^ (r & 3)) * 8;
    glds16(&A[(size_t)(m0 + r) * DIM + cc], As[0] + i * 8);
    glds16(&W[(size_t)(n0 + r) * DIM + cc], Bs[0] + i * 8);
  }

  for (int kt = 0; kt < 32; kt++) {
    __syncthreads();
    if (kt < 31) {
      int k0 = (kt + 1) * 32, nb = (kt + 1) & 1;
      for (int t = 0; t < 2; t++) {
        int i = tid + t * 256, r = i >> 2, p = i & 3, cc = (p ^ (r & 3)) * 8;
        glds16(&A[(size_t)(m0 + r) * DIM + k0 + cc], As[nb] + i * 8);
        glds16(&W[(size_t)(n0 + r) * DIM + k0 + cc], Bs[nb] + i * 8);
      }
    }
    int bb = kt & 1;
    s16x8 af[4], bf[4];
    for (int i = 0; i < 4; i++)
      af[i] = *(const s16x8*)&As[bb][(rowoff + i * 16 + ln) * 32 + ((quad ^ (ln & 3)) * 8)];
    for (int j = 0; j < 4; j++)
      bf[j] = *(const s16x8*)&Bs[bb][(coloff + j * 16 + ln) * 32 + ((quad ^ (ln & 3)) * 8)];
    for (int i = 0; i < 4; i++)
      for (int j = 0; j < 4; j++)
        acc[i][j] = __builtin_amdgcn_mfma_f32_16x16x32_bf16(af[i], bf[j], acc[i][j], 0, 0, 0);
  }

  for (int i = 0; i < 4; i++)
    for (int j = 0; j < 4; j++)
      for (int r = 0; r < 4; r++) {
        int row = m0 + rowoff + i * 16 + quad * 4 + r;
        int col = n0 + coloff + j * 16 + ln;
        out[(size_t)row * DIM + col] = acc[i][j][r] + bo[col] + resid[(size_t)row * DIM + col];
      }
}

// ---------------- launch ----------------
extern "C" void kernel_launch(void* const* d_in, const int* in_sizes, int n_in,
                              void* d_out, int out_size, void* d_ws, size_t ws_size,
                              hipStream_t stream) {
  const float* cs = (const float*)d_in[0];
  const float* sn = (const float*)d_in[1];
  const float* x  = (const float*)d_in[2];
  const float* Wq = (const float*)d_in[4];  const float* bq = (const float*)d_in[5];
  const float* Wk = (const float*)d_in[6];  const float* bk = (const float*)d_in[7];
  const float* Wv = (const float*)d_in[8];  const float* bv = (const float*)d_in[9];
  const float* Wo = (const float*)d_in[10]; const float* bo = (const float*)d_in[11];
  float* out = (float*)d_out;

  char* ws = (char*)d_ws;
  u16* Xr = (u16*)(ws + (size_t)0);
  u16* Wb = (u16*)(ws + ((size_t)8 << 20));
  u16* Qb = (u16*)(ws + ((size_t)16 << 20));
  u16* Kb = (u16*)(ws + ((size_t)24 << 20));
  u16* Vt = (u16*)(ws + ((size_t)32 << 20));
  u16* Ab = (u16*)(ws + ((size_t)40 << 20));

  prep<<<8192, 256, 0, stream>>>(x, cs, sn, Wq, Wk, Wv, Wo, Xr, Wb);
  qkv_gemm<<<dim3(32, 8, 3), 256, 0, stream>>>(Xr, Wb, bq, bk, bv, Qb, Kb, Vt);
  attn_kernel<<<512, 256, 0, stream>>>(Qb, Kb, Vt, Ab);
  out_gemm<<<dim3(32, 8), 256, 0, stream>>>(Ab, Wb + ((size_t)3 << 20), bo, x, out);
}